// Round 2
// baseline (554.663 us; speedup 1.0000x reference)
//
#include <hip/hip_runtime.h>
#include <stdint.h>

// Problem constants
#define ENC2 1024   // 2*ENC_HID = K of main GEMM
#define DECH 1024
#define ADIM 1024   // N (attn dim)
#define BB   32
#define SS   1024

typedef _Float16 half_t;
typedef __attribute__((ext_vector_type(8))) _Float16 half8;
typedef __attribute__((ext_vector_type(4))) float    f32x4;

// async global->LDS, 16B per lane; lds dest = wave-uniform base + lane*16
__device__ __forceinline__ void dma16(const half_t* g, half_t* l) {
    __builtin_amdgcn_global_load_lds((const __attribute__((address_space(1))) void*)g,
                                     (__attribute__((address_space(3))) void*)l,
                                     16, 0, 0);
}

// ---------------------------------------------------------------------------
// K0: build swizzled fp16 W_enc^T. Region (nb,ks) = 16KB covering
// n-rows r=0..255 (n = nb*256+r) x k-chunks c=0..3 (k = ks*32+c*8+e).
// Chunk stored at half-offset region + r*32 + pos*8, pos = c ^ ((r>>1)&3).
// Wave-linear DMA fill of a region then yields conflict-free ds_read_b128
// (8 distinct bank groups, 2 lanes each, per quarter-wave).
// ---------------------------------------------------------------------------
__global__ __launch_bounds__(256) void k_wt(const float* __restrict__ W,
                                            half_t* __restrict__ Wt2) {
    __shared__ float tile[32][257];
    const int nb = blockIdx.x >> 5;   // 0..3
    const int ks = blockIdx.x & 31;   // 0..31
    const int t = threadIdx.x;
    #pragma unroll
    for (int i = 0; i < 32; i++) {
        int idx = t + i * 256;
        int kr = idx >> 8, n = idx & 255;
        tile[kr][n] = W[(size_t)(DECH + ks * 32 + kr) * ADIM + nb * 256 + n];
    }
    __syncthreads();
    half_t* reg = Wt2 + ((size_t)(nb * 32 + ks) << 13);   // 8192 halfs/region
    #pragma unroll
    for (int i = 0; i < 4; i++) {
        int cid = t + i * 256;            // 0..1023 chunk id
        int r = cid >> 2, pos = cid & 3;
        int c = pos ^ ((r >> 1) & 3);
        half8 h;
        #pragma unroll
        for (int e = 0; e < 8; e++) h[e] = (half_t)tile[c * 8 + e][r];
        *(half8*)(reg + r * 32 + pos * 8) = h;
    }
}

// ---------------------------------------------------------------------------
// K1: decp[b][a] = dh[b] . W_dec[:,a]  (fp32 partials via atomics; bias added
// in k_main). Grid 128 = 16 col-tiles(64) x 8 k-chunks(128). W read once,
// coalesced; dh via scalar loads (k wave-uniform).
// ---------------------------------------------------------------------------
__global__ __launch_bounds__(256) void k_decp(const float* __restrict__ dh,
                                              const float* __restrict__ W,
                                              float* __restrict__ decp) {
    const int ct = blockIdx.x & 15;
    const int kc = blockIdx.x >> 4;
    const int t = threadIdx.x;
    const int col = ct * 64 + (t & 63);
    const int wv = __builtin_amdgcn_readfirstlane(t >> 6);  // wave-uniform
    const int k0 = kc * 128 + wv * 32;
    float wreg[32];
    #pragma unroll
    for (int kk = 0; kk < 32; kk++)
        wreg[kk] = W[(size_t)(k0 + kk) * ADIM + col];
    #pragma unroll 4
    for (int b = 0; b < 32; b++) {
        float s = 0.f;
        #pragma unroll
        for (int kk = 0; kk < 32; kk++)
            s += dh[b * 1024 + k0 + kk] * wreg[kk];
        atomicAdd(&decp[b * 1024 + col], s);
    }
}

// ---------------------------------------------------------------------------
// K2: fused GEMM(fp16 MFMA) + tanh + dot(v) -> scores (fp32 atomics)
// Tile 128x256, BK=32, 512 thr. Grid 1024 = 256 m-tiles x 4 n-tiles.
// LDS 53248B -> 3 blocks/CU (24 waves). B staged by global_load_lds from
// pre-swizzled Wt2 (no VGPR round-trip, no write conflicts); A staged
// manually (fp32->fp16 convert) with 16-rows/quarter-wave writes (2/bank).
// ---------------------------------------------------------------------------
#define BM 128
#define BN 256
#define BK 32
#define LDA 40   // 20 dwords stride: frag reads/writes hit 2/bank (optimal)

__global__ __launch_bounds__(512, 6) void k_main(const float* __restrict__ enc,
                                                 const half_t* __restrict__ Wt2,
                                                 const float* __restrict__ decp,
                                                 const float* __restrict__ bias,
                                                 const float* __restrict__ v,
                                                 float* __restrict__ scores) {
    __shared__ half_t lsA[2][BM][LDA];    // 20480 B
    __shared__ half_t lsB[2][BN * BK];    // 32768 B, swizzled chunk layout

    const int bid = blockIdx.x;
    const int nb = bid & 3;           // n-tile: A-sharers adjacent (concurrent)
    const int mi = bid >> 2;          // 0..255 m-tile
    const int m0 = mi * BM;
    const int n0 = nb * BN;
    const int t = threadIdx.x;
    const int w = t >> 6, L = t & 63;
    const int wm = w & 1, wn = w >> 1;        // 2x4 wave grid, 64x64 tiles
    const int lane15 = L & 15, quad = L >> 4;
    const int batch = mi >> 3;                // 8 m-tiles per batch row-block

    // A staging: thread -> (row, 8-float chunk); 16 rows/quarter-wave
    const int arow = t & 127;
    const int akc  = (t >> 7) * 8;
    const float* Aptr = enc + (size_t)(m0 + arow) * ENC2 + akc;

    // B staging: DMA regions
    const half_t* Bbase = Wt2 + ((size_t)(nb * 32) << 13);

    // epilogue per-lane column constants
    float vv[4], dp[4];
    #pragma unroll
    for (int sn = 0; sn < 4; sn++) {
        int ng = n0 + wn * 64 + sn * 16 + lane15;
        vv[sn] = v[ng];
        dp[sn] = decp[(size_t)batch * ADIM + ng] + bias[ng];
    }

    f32x4 acc[4][4];
    #pragma unroll
    for (int i = 0; i < 4; i++)
        #pragma unroll
        for (int j = 0; j < 4; j++) acc[i][j] = (f32x4)0.f;

    float4 ra0, ra1;
    auto loadA = [&](int ks) {
        const float* p = Aptr + ks * BK;
        ra0 = *(const float4*)p;
        ra1 = *(const float4*)(p + 4);
    };
    auto writeA = [&](int pb) {
        half8 ha;
        ha[0] = (half_t)ra0.x; ha[1] = (half_t)ra0.y;
        ha[2] = (half_t)ra0.z; ha[3] = (half_t)ra0.w;
        ha[4] = (half_t)ra1.x; ha[5] = (half_t)ra1.y;
        ha[6] = (half_t)ra1.z; ha[7] = (half_t)ra1.w;
        *(half8*)&lsA[pb][arow][akc] = ha;
    };
    auto dmaB = [&](int ks, int pb) {
        // wave w fills j = 2w, 2w+1 (1024 B each); lds dest wave-uniform
        #pragma unroll
        for (int jj = 0; jj < 2; jj++) {
            int j = 2 * w + jj;
            dma16(Bbase + ((size_t)ks << 13) + j * 512 + L * 8,
                  &lsB[pb][j * 512]);
        }
    };

    // prologue
    dmaB(0, 0);
    loadA(0);
    writeA(0);
    loadA(1);
    __syncthreads();

    for (int ks = 0; ks < ENC2 / BK; ks++) {
        const int cur = ks & 1;
        if (ks < ENC2 / BK - 1) {
            dmaB(ks + 1, cur ^ 1);    // after prev barrier: cur^1 free
            writeA(cur ^ 1);          // regs for ks+1
            if (ks < ENC2 / BK - 2) loadA(ks + 2);
        }
        half8 af[4], bf[4];
        #pragma unroll
        for (int sm = 0; sm < 4; sm++)
            af[sm] = *(const half8*)&lsA[cur][wm * 64 + sm * 16 + lane15][quad * 8];
        #pragma unroll
        for (int sn = 0; sn < 4; sn++) {
            int r = wn * 64 + sn * 16 + lane15;
            int pos = quad ^ ((r >> 1) & 3);
            bf[sn] = *(const half8*)&lsB[cur][r * 32 + pos * 8];
        }
        #pragma unroll
        for (int sm = 0; sm < 4; sm++)
            #pragma unroll
            for (int sn = 0; sn < 4; sn++)
                acc[sm][sn] = __builtin_amdgcn_mfma_f32_16x16x32_f16(
                    af[sm], bf[sn], acc[sm][sn], 0, 0, 0);
        __syncthreads();
    }

    // epilogue: tanh(acc + decp + bias) . v, reduce over 16 col-lanes
    // C/D layout: row(m) = quad*4 + reg, col(n) = lane15
    #pragma unroll
    for (int sm = 0; sm < 4; sm++) {
        #pragma unroll
        for (int rr = 0; rr < 4; rr++) {
            float s = 0.f;
            #pragma unroll
            for (int sn = 0; sn < 4; sn++) {
                float x = acc[sm][sn][rr] + dp[sn];
                float e  = __builtin_amdgcn_exp2f(x * 2.8853900817779268f);
                float th = 1.f - 2.f * __builtin_amdgcn_rcpf(e + 1.f);
                s += th * vv[sn];
            }
            s += __shfl_xor(s, 1, 64);
            s += __shfl_xor(s, 2, 64);
            s += __shfl_xor(s, 4, 64);
            s += __shfl_xor(s, 8, 64);
            if (lane15 == 0) {
                int mlocal = wm * 64 + sm * 16 + quad * 4 + rr;
                atomicAdd(&scores[(size_t)m0 + mlocal], s);
            }
        }
    }
}

// ---------------------------------------------------------------------------
// K3: row softmax over S=1024 per batch row
// ---------------------------------------------------------------------------
__global__ __launch_bounds__(256) void k_softmax(const float* __restrict__ scores,
                                                 float* __restrict__ out) {
    __shared__ float red[8];
    const int b = blockIdx.x, t = threadIdx.x;
    const float* row = scores + (size_t)b * SS;
    float x[4];
    #pragma unroll
    for (int i = 0; i < 4; i++) x[i] = row[t + i * 256];
    float mx = fmaxf(fmaxf(x[0], x[1]), fmaxf(x[2], x[3]));
    #pragma unroll
    for (int d = 1; d < 64; d <<= 1) mx = fmaxf(mx, __shfl_xor(mx, d, 64));
    if ((t & 63) == 0) red[t >> 6] = mx;
    __syncthreads();
    mx = fmaxf(fmaxf(red[0], red[1]), fmaxf(red[2], red[3]));
    float e[4], s = 0.f;
    #pragma unroll
    for (int i = 0; i < 4; i++) {
        e[i] = __builtin_amdgcn_exp2f((x[i] - mx) * 1.4426950408889634f);
        s += e[i];
    }
    #pragma unroll
    for (int d = 1; d < 64; d <<= 1) s += __shfl_xor(s, d, 64);
    if ((t & 63) == 0) red[4 + (t >> 6)] = s;
    __syncthreads();
    s = red[4] + red[5] + red[6] + red[7];
    float inv = 1.f / s;
    #pragma unroll
    for (int i = 0; i < 4; i++) out[(size_t)b * SS + t + i * 256] = e[i] * inv;
}

// ---------------------------------------------------------------------------
extern "C" void kernel_launch(void* const* d_in, const int* in_sizes, int n_in,
                              void* d_out, int out_size, void* d_ws, size_t ws_size,
                              hipStream_t stream) {
    const float* dh   = (const float*)d_in[0];  // (32,1024)
    const float* enc  = (const float*)d_in[1];  // (32,1024,1024)
    const float* W    = (const float*)d_in[2];  // (2048,1024)
    const float* bias = (const float*)d_in[3];  // (1024,)
    const float* v    = (const float*)d_in[4];  // (1024,)
    float* out = (float*)d_out;

    char* ws = (char*)d_ws;
    half_t* Wt2   = (half_t*)ws;                                     // 2 MB
    float*  decp  = (float*)(ws + 2u * 1024 * 1024);                 // 128 KB
    float*  scores = (float*)(ws + 2u * 1024 * 1024 + 128 * 1024);   // 128 KB

    // zero decp+scores (contiguous 256 KB) BEFORE k_decp's atomics
    hipMemsetAsync(ws + 2u * 1024 * 1024, 0, 256 * 1024, stream);
    k_wt  <<<128, 256, 0, stream>>>(W, Wt2);
    k_decp<<<128, 256, 0, stream>>>(dh, W, decp);
    k_main<<<1024, 512, 0, stream>>>(enc, Wt2, decp, bias, v, scores);
    k_softmax<<<32, 256, 0, stream>>>(scores, out);
}

// Round 4
// 508.357 us; speedup vs baseline: 1.0911x; 1.0911x over previous
//
#include <hip/hip_runtime.h>
#include <stdint.h>

// Problem constants
#define ENC2 1024   // 2*ENC_HID = K of main GEMM
#define DECH 1024
#define ADIM 1024   // N (attn dim)
#define BB   32
#define SS   1024

typedef _Float16 half_t;
typedef __attribute__((ext_vector_type(8))) _Float16 half8;
typedef __attribute__((ext_vector_type(4))) float    f32x4;

// async global->LDS, 16B per lane; lds dest = wave-uniform base + lane*16
__device__ __forceinline__ void dma16(const half_t* g, half_t* l) {
    __builtin_amdgcn_global_load_lds((const __attribute__((address_space(1))) void*)g,
                                     (__attribute__((address_space(3))) void*)l,
                                     16, 0, 0);
}

// ---------------------------------------------------------------------------
// K0: build swizzled fp16 W_enc^T. Region (nb,ks) = 16KB covering
// n-rows r=0..255 (n = nb*256+r) x k-chunks c=0..3 (k = ks*32+c*8+e).
// Chunk at half-offset region + r*32 + pos*8, pos = c ^ ((r>>1)&3), so the
// wave-linear DMA fill yields conflict-free ds_read_b128 in k_main.
// ---------------------------------------------------------------------------
__global__ __launch_bounds__(256) void k_wt(const float* __restrict__ W,
                                            half_t* __restrict__ Wt2) {
    __shared__ float tile[32][257];
    const int nb = blockIdx.x >> 5;   // 0..3
    const int ks = blockIdx.x & 31;   // 0..31
    const int t = threadIdx.x;
    #pragma unroll
    for (int i = 0; i < 32; i++) {
        int idx = t + i * 256;
        int kr = idx >> 8, n = idx & 255;
        tile[kr][n] = W[(size_t)(DECH + ks * 32 + kr) * ADIM + nb * 256 + n];
    }
    __syncthreads();
    half_t* reg = Wt2 + ((size_t)(nb * 32 + ks) << 13);   // 8192 halfs/region
    #pragma unroll
    for (int i = 0; i < 4; i++) {
        int cid = t + i * 256;            // 0..1023 chunk id
        int r = cid >> 2, pos = cid & 3;
        int c = pos ^ ((r >> 1) & 3);
        half8 h;
        #pragma unroll
        for (int e = 0; e < 8; e++) h[e] = (half_t)tile[c * 8 + e][r];
        *(half8*)(reg + r * 32 + pos * 8) = h;
    }
}

// ---------------------------------------------------------------------------
// K1: decp[b][a] = dh[b] . W_dec[:,a]  (fp32, no atomics, no pre-zero).
// Grid 16 col-tiles(64) x 256 thr; wave w owns k-chunk of 256; LDS reduce.
// ---------------------------------------------------------------------------
__global__ __launch_bounds__(256) void k_decp(const float* __restrict__ dh,
                                              const float* __restrict__ W,
                                              float* __restrict__ decp) {
    __shared__ float red[4][BB][64];   // 32 KB
    const int t = threadIdx.x;
    const int col = blockIdx.x * 64 + (t & 63);
    const int w = t >> 6;
    float s[BB];
    #pragma unroll
    for (int b = 0; b < BB; b++) s[b] = 0.f;
    for (int kk = 0; kk < 256; kk++) {
        int k = w * 256 + kk;
        float wv = W[(size_t)k * ADIM + col];
        #pragma unroll
        for (int b = 0; b < BB; b++)
            s[b] += dh[b * DECH + k] * wv;
    }
    #pragma unroll
    for (int b = 0; b < BB; b++) red[w][b][t & 63] = s[b];
    __syncthreads();
    if (w == 0) {
        for (int b = 0; b < BB; b++)
            decp[(size_t)b * ADIM + col] =
                red[0][b][t] + red[1][b][t] + red[2][b][t] + red[3][b][t];
    }
}

// ---------------------------------------------------------------------------
// K2: fused GEMM(fp16 MFMA) + tanh + dot(v) -> per-n-tile partial scores.
// Tile 128x256, BK=32, 512 thr. Grid 1024 = 256 m-tiles x 4 n-tiles.
// Sharer mapping: mi = (bid>>5)*8 + (bid&7), nb = (bid>>3)&3 -> the 4 blocks
// sharing an A m-tile are within 32 bids AND congruent mod 8 -> same XCD,
// co-temporal -> A fetched from HBM ~once.
// LDS 53248B -> 3 blocks/CU. B via global_load_lds from swizzled Wt2.
// Epilogue: per-wave partials reduced ACROSS wn THROUGH LDS (round-3 bug:
// plain stores raced across the 4 wn waves), then one store per row per
// block into this nb's partial buffer; k_softmax sums the 4 nb partials.
// ---------------------------------------------------------------------------
#define BM 128
#define BN 256
#define BK 32
#define LDA 40

__global__ __launch_bounds__(512) void k_main(const float* __restrict__ enc,
                                              const half_t* __restrict__ Wt2,
                                              const float* __restrict__ decp,
                                              const float* __restrict__ bias,
                                              const float* __restrict__ v,
                                              float* __restrict__ scores_part) {
    __shared__ half_t lsA[2][BM][LDA];    // 20480 B
    __shared__ half_t lsB[2][BN * BK];    // 32768 B, swizzled chunk layout

    const int bid = blockIdx.x;
    const int mi = (bid >> 5) * 8 + (bid & 7);   // 0..255
    const int nb = (bid >> 3) & 3;               // 0..3
    const int m0 = mi * BM;
    const int n0 = nb * BN;
    const int t = threadIdx.x;
    const int w = t >> 6, L = t & 63;
    const int wm = w & 1, wn = w >> 1;        // 2x4 wave grid, 64x64 tiles
    const int lane15 = L & 15, quad = L >> 4;
    const int batch = mi >> 3;                // 8 m-tiles per batch row

    // A staging: thread -> (row, 8-float chunk)
    const int arow = t & 127;
    const int akc  = (t >> 7) * 8;
    const float* Aptr = enc + (size_t)(m0 + arow) * ENC2 + akc;

    const half_t* Bbase = Wt2 + ((size_t)(nb * 32) << 13);

    // epilogue per-lane column constants
    float vv[4], dp[4];
    #pragma unroll
    for (int sn = 0; sn < 4; sn++) {
        int ng = n0 + wn * 64 + sn * 16 + lane15;
        vv[sn] = v[ng];
        dp[sn] = decp[(size_t)batch * ADIM + ng] + bias[ng];
    }

    f32x4 acc[4][4];
    #pragma unroll
    for (int i = 0; i < 4; i++)
        #pragma unroll
        for (int j = 0; j < 4; j++) acc[i][j] = (f32x4)0.f;

    float4 ra0, ra1;
    auto loadA = [&](int ks) {
        const float* p = Aptr + ks * BK;
        ra0 = *(const float4*)p;
        ra1 = *(const float4*)(p + 4);
    };
    auto writeA = [&](int pb) {
        half8 ha;
        ha[0] = (half_t)ra0.x; ha[1] = (half_t)ra0.y;
        ha[2] = (half_t)ra0.z; ha[3] = (half_t)ra0.w;
        ha[4] = (half_t)ra1.x; ha[5] = (half_t)ra1.y;
        ha[6] = (half_t)ra1.z; ha[7] = (half_t)ra1.w;
        *(half8*)&lsA[pb][arow][akc] = ha;
    };
    auto dmaB = [&](int ks, int pb) {
        #pragma unroll
        for (int jj = 0; jj < 2; jj++) {
            int j = 2 * w + jj;
            dma16(Bbase + ((size_t)ks << 13) + j * 512 + L * 8,
                  &lsB[pb][j * 512]);
        }
    };

    // prologue
    dmaB(0, 0);
    loadA(0);
    writeA(0);
    loadA(1);
    __syncthreads();

    for (int ks = 0; ks < ENC2 / BK; ks++) {
        const int cur = ks & 1;
        if (ks < ENC2 / BK - 1) {
            dmaB(ks + 1, cur ^ 1);
            writeA(cur ^ 1);
            if (ks < ENC2 / BK - 2) loadA(ks + 2);
        }
        half8 af[4], bf[4];
        #pragma unroll
        for (int sm = 0; sm < 4; sm++)
            af[sm] = *(const half8*)&lsA[cur][wm * 64 + sm * 16 + lane15][quad * 8];
        #pragma unroll
        for (int sn = 0; sn < 4; sn++) {
            int r = wn * 64 + sn * 16 + lane15;
            int pos = quad ^ ((r >> 1) & 3);
            bf[sn] = *(const half8*)&lsB[cur][r * 32 + pos * 8];
        }
        #pragma unroll
        for (int sm = 0; sm < 4; sm++)
            #pragma unroll
            for (int sn = 0; sn < 4; sn++)
                acc[sm][sn] = __builtin_amdgcn_mfma_f32_16x16x32_f16(
                    af[sm], bf[sn], acc[sm][sn], 0, 0, 0);
        __syncthreads();
    }

    // epilogue: tanh(acc + decp + bias) . v
    // C/D layout: row(m) = quad*4 + reg, col(n) = lane15
    // Step 1: shuffle-reduce over the 16 col-lanes -> per-wave partial
    // Step 2: LDS reduce across the 4 wn waves (reuse lsA; all waves are
    //         past the final K-loop barrier so the buffer is dead)
    float* redL = (float*)&lsA[0][0][0];   // [wn][128] rows, 2 KB used
    #pragma unroll
    for (int sm = 0; sm < 4; sm++) {
        #pragma unroll
        for (int rr = 0; rr < 4; rr++) {
            float s = 0.f;
            #pragma unroll
            for (int sn = 0; sn < 4; sn++) {
                float x = acc[sm][sn][rr] + dp[sn];
                float e  = __builtin_amdgcn_exp2f(x * 2.8853900817779268f);
                float th = 1.f - 2.f * __builtin_amdgcn_rcpf(e + 1.f);
                s += th * vv[sn];
            }
            s += __shfl_xor(s, 1, 64);
            s += __shfl_xor(s, 2, 64);
            s += __shfl_xor(s, 4, 64);
            s += __shfl_xor(s, 8, 64);
            if (lane15 == 0) {
                int mlocal = wm * 64 + sm * 16 + quad * 4 + rr;
                redL[wn * 128 + mlocal] = s;
            }
        }
    }
    __syncthreads();
    if (t < 128) {
        float s = redL[t] + redL[128 + t] + redL[256 + t] + redL[384 + t];
        scores_part[((size_t)nb << 15) + m0 + t] = s;
    }
}

// ---------------------------------------------------------------------------
// K3: sum 4 partials + row softmax over S=1024 per batch row
// ---------------------------------------------------------------------------
__global__ __launch_bounds__(256) void k_softmax(const float* __restrict__ sp,
                                                 float* __restrict__ out) {
    __shared__ float red[8];
    const int b = blockIdx.x, t = threadIdx.x;
    float x[4];
    #pragma unroll
    for (int i = 0; i < 4; i++) {
        size_t idx = (size_t)b * SS + t + i * 256;
        x[i] = sp[idx] + sp[(1u << 15) + idx] + sp[(2u << 15) + idx] +
               sp[(3u << 15) + idx];
    }
    float mx = fmaxf(fmaxf(x[0], x[1]), fmaxf(x[2], x[3]));
    #pragma unroll
    for (int d = 1; d < 64; d <<= 1) mx = fmaxf(mx, __shfl_xor(mx, d, 64));
    if ((t & 63) == 0) red[t >> 6] = mx;
    __syncthreads();
    mx = fmaxf(fmaxf(red[0], red[1]), fmaxf(red[2], red[3]));
    float e[4], s = 0.f;
    #pragma unroll
    for (int i = 0; i < 4; i++) {
        e[i] = __builtin_amdgcn_exp2f((x[i] - mx) * 1.4426950408889634f);
        s += e[i];
    }
    #pragma unroll
    for (int d = 1; d < 64; d <<= 1) s += __shfl_xor(s, d, 64);
    if ((t & 63) == 0) red[4 + (t >> 6)] = s;
    __syncthreads();
    s = red[4] + red[5] + red[6] + red[7];
    float inv = 1.f / s;
    #pragma unroll
    for (int i = 0; i < 4; i++) out[(size_t)b * SS + t + i * 256] = e[i] * inv;
}

// ---------------------------------------------------------------------------
extern "C" void kernel_launch(void* const* d_in, const int* in_sizes, int n_in,
                              void* d_out, int out_size, void* d_ws, size_t ws_size,
                              hipStream_t stream) {
    const float* dh   = (const float*)d_in[0];  // (32,1024)
    const float* enc  = (const float*)d_in[1];  // (32,1024,1024)
    const float* W    = (const float*)d_in[2];  // (2048,1024)
    const float* bias = (const float*)d_in[3];  // (1024,)
    const float* v    = (const float*)d_in[4];  // (1024,)
    float* out = (float*)d_out;

    char* ws = (char*)d_ws;
    half_t* Wt2    = (half_t*)ws;                                    // 2 MB
    float*  decp   = (float*)(ws + 2u * 1024 * 1024);                // 128 KB
    float*  spart  = (float*)(ws + 2u * 1024 * 1024 + 128 * 1024);   // 512 KB

    k_wt     <<<128, 256, 0, stream>>>(W, Wt2);
    k_decp   <<<16, 256, 0, stream>>>(dh, W, decp);
    k_main   <<<1024, 512, 0, stream>>>(enc, Wt2, decp, bias, v, spart);
    k_softmax<<<32, 256, 0, stream>>>(spart, out);
}

// Round 5
// 307.983 us; speedup vs baseline: 1.8010x; 1.6506x over previous
//
#include <hip/hip_runtime.h>
#include <stdint.h>

// Problem constants
#define ENC2 1024   // 2*ENC_HID = K of main GEMM
#define DECH 1024
#define ADIM 1024   // N (attn dim)
#define BB   32
#define SS   1024

typedef _Float16 half_t;
typedef __attribute__((ext_vector_type(8))) _Float16 half8;
typedef __attribute__((ext_vector_type(4))) float    f32x4;

// async global->LDS, 16B per lane; lds dest = wave-uniform base + lane*16
__device__ __forceinline__ void dma16(const half_t* g, half_t* l) {
    __builtin_amdgcn_global_load_lds((const __attribute__((address_space(1))) void*)g,
                                     (__attribute__((address_space(3))) void*)l,
                                     16, 0, 0);
}

// ---------------------------------------------------------------------------
// K0: build swizzled fp16 W_enc^T (region/chunk layout as before).
// ---------------------------------------------------------------------------
__global__ __launch_bounds__(256) void k_wt(const float* __restrict__ W,
                                            half_t* __restrict__ Wt2) {
    __shared__ float tile[32][257];
    const int nb = blockIdx.x >> 5;   // 0..3
    const int ks = blockIdx.x & 31;   // 0..31
    const int t = threadIdx.x;
    #pragma unroll
    for (int i = 0; i < 32; i++) {
        int idx = t + i * 256;
        int kr = idx >> 8, n = idx & 255;
        tile[kr][n] = W[(size_t)(DECH + ks * 32 + kr) * ADIM + nb * 256 + n];
    }
    __syncthreads();
    half_t* reg = Wt2 + ((size_t)(nb * 32 + ks) << 13);   // 8192 halfs/region
    #pragma unroll
    for (int i = 0; i < 4; i++) {
        int cid = t + i * 256;            // 0..1023 chunk id
        int r = cid >> 2, pos = cid & 3;
        int c = pos ^ ((r >> 1) & 3);
        half8 h;
        #pragma unroll
        for (int e = 0; e < 8; e++) h[e] = (half_t)tile[c * 8 + e][r];
        *(half8*)(reg + r * 32 + pos * 8) = h;
    }
}

// ---------------------------------------------------------------------------
// K1a: split-K stage 1. Grid 128 = 16 col-tiles(64) x 8 k-chunks(128).
// Wave w owns k sub-range 32; LDS-reduce across waves; write partials.
// (Round-4 k_decp had grid 16 -> 6% of the GPU and ~250 us of exposed HBM
// latency; this spreads the same 4 MB W read over 128 CUs.)
// ---------------------------------------------------------------------------
__global__ __launch_bounds__(256) void k_dp1(const float* __restrict__ dh,
                                             const float* __restrict__ W,
                                             float* __restrict__ part) {
    __shared__ float red[4][BB][64];   // 32 KB
    const int t = threadIdx.x;
    const int ct = blockIdx.x & 15;
    const int kc = blockIdx.x >> 4;    // 0..7
    const int col = ct * 64 + (t & 63);
    const int w = t >> 6;
    const int k0 = kc * 128 + w * 32;
    float wreg[32];
    #pragma unroll
    for (int kk = 0; kk < 32; kk++)
        wreg[kk] = W[(size_t)(k0 + kk) * ADIM + col];
    float s[BB];
    #pragma unroll
    for (int b = 0; b < BB; b++) s[b] = 0.f;
    #pragma unroll
    for (int kk = 0; kk < 32; kk++) {
        #pragma unroll
        for (int b = 0; b < BB; b++)
            s[b] += dh[b * DECH + k0 + kk] * wreg[kk];
    }
    #pragma unroll
    for (int b = 0; b < BB; b++) red[w][b][t & 63] = s[b];
    __syncthreads();
    if (t < 64) {
        for (int b = 0; b < BB; b++)
            part[((size_t)kc * BB + b) * ADIM + ct * 64 + t] =
                red[0][b][t] + red[1][b][t] + red[2][b][t] + red[3][b][t];
    }
}

// ---------------------------------------------------------------------------
// K1b: split-K stage 2: decp[b][a] = sum_kc part + bias[a]
// ---------------------------------------------------------------------------
__global__ __launch_bounds__(256) void k_dp2(const float* __restrict__ part,
                                             const float* __restrict__ bias,
                                             float* __restrict__ decp) {
    const int i = blockIdx.x * 256 + threadIdx.x;   // 0..32767
    float s = bias[i & (ADIM - 1)];
    #pragma unroll
    for (int kc = 0; kc < 8; kc++)
        s += part[(size_t)kc * BB * ADIM + i];
    decp[i] = s;
}

// ---------------------------------------------------------------------------
// K2: fused GEMM(fp16 MFMA) + tanh + dot(v) -> per-n-tile partial scores.
// Tile 128x256, BK=32, 512 thr. Grid 1024 = 256 m-tiles x 4 n-tiles.
// __launch_bounds__(512,4): cap = 512/4 = 128 total regs = 64 AGPR(acc) +
// 64 arch -> 2 blocks/CU (round 4: 68 arch + 64 agpr = 132 -> 1 block/CU,
// 22% occupancy, barrier drains fully exposed). vv/dp loads deferred to the
// epilogue to cut in-loop live regs; bias pre-folded into decp by k_dp2.
// ---------------------------------------------------------------------------
#define BM 128
#define BN 256
#define BK 32
#define LDA 40

__global__ __launch_bounds__(512, 4) void k_main(const float* __restrict__ enc,
                                                 const half_t* __restrict__ Wt2,
                                                 const float* __restrict__ decp,
                                                 const float* __restrict__ v,
                                                 float* __restrict__ scores_part) {
    __shared__ half_t lsA[2][BM][LDA];    // 20480 B
    __shared__ half_t lsB[2][BN * BK];    // 32768 B, swizzled chunk layout

    const int bid = blockIdx.x;
    const int mi = (bid >> 5) * 8 + (bid & 7);   // 0..255
    const int nb = (bid >> 3) & 3;               // 0..3
    const int m0 = mi * BM;
    const int t = threadIdx.x;
    const int w = t >> 6, L = t & 63;
    const int wm = w & 1, wn = w >> 1;        // 2x4 wave grid, 64x64 tiles
    const int lane15 = L & 15, quad = L >> 4;

    // A staging: thread -> (row, 8-float chunk)
    const int arow = t & 127;
    const int akc  = (t >> 7) * 8;
    const float* Aptr = enc + (size_t)(m0 + arow) * ENC2 + akc;

    const half_t* Bbase = Wt2 + ((size_t)(nb * 32) << 13);

    f32x4 acc[4][4];
    #pragma unroll
    for (int i = 0; i < 4; i++)
        #pragma unroll
        for (int j = 0; j < 4; j++) acc[i][j] = (f32x4)0.f;

    float4 ra0, ra1;
    auto loadA = [&](int ks) {
        const float* p = Aptr + ks * BK;
        ra0 = *(const float4*)p;
        ra1 = *(const float4*)(p + 4);
    };
    auto writeA = [&](int pb) {
        half8 ha;
        ha[0] = (half_t)ra0.x; ha[1] = (half_t)ra0.y;
        ha[2] = (half_t)ra0.z; ha[3] = (half_t)ra0.w;
        ha[4] = (half_t)ra1.x; ha[5] = (half_t)ra1.y;
        ha[6] = (half_t)ra1.z; ha[7] = (half_t)ra1.w;
        *(half8*)&lsA[pb][arow][akc] = ha;
    };
    auto dmaB = [&](int ks, int pb) {
        #pragma unroll
        for (int jj = 0; jj < 2; jj++) {
            int j = 2 * w + jj;
            dma16(Bbase + ((size_t)ks << 13) + j * 512 + L * 8,
                  &lsB[pb][j * 512]);
        }
    };

    // prologue
    dmaB(0, 0);
    loadA(0);
    writeA(0);
    loadA(1);
    __syncthreads();

    for (int ks = 0; ks < ENC2 / BK; ks++) {
        const int cur = ks & 1;
        if (ks < ENC2 / BK - 1) {
            dmaB(ks + 1, cur ^ 1);
            writeA(cur ^ 1);
            if (ks < ENC2 / BK - 2) loadA(ks + 2);
        }
        half8 af[4], bf[4];
        #pragma unroll
        for (int sm = 0; sm < 4; sm++)
            af[sm] = *(const half8*)&lsA[cur][wm * 64 + sm * 16 + lane15][quad * 8];
        #pragma unroll
        for (int sn = 0; sn < 4; sn++) {
            int r = wn * 64 + sn * 16 + lane15;
            int pos = quad ^ ((r >> 1) & 3);
            bf[sn] = *(const half8*)&lsB[cur][r * 32 + pos * 8];
        }
        #pragma unroll
        for (int sm = 0; sm < 4; sm++)
            #pragma unroll
            for (int sn = 0; sn < 4; sn++)
                acc[sm][sn] = __builtin_amdgcn_mfma_f32_16x16x32_f16(
                    af[sm], bf[sn], acc[sm][sn], 0, 0, 0);
        __syncthreads();
    }

    // epilogue per-lane column constants (loaded HERE, not before the loop,
    // to keep in-loop live regs under the 64-arch budget)
    const int batch = mi >> 3;
    float vv[4], dp[4];
    #pragma unroll
    for (int sn = 0; sn < 4; sn++) {
        int ng = nb * BN + wn * 64 + sn * 16 + lane15;
        vv[sn] = v[ng];
        dp[sn] = decp[(size_t)batch * ADIM + ng];   // bias already folded in
    }

    // tanh(acc + dp) . v; shuffle-reduce 16 col-lanes, LDS-reduce across wn
    // C/D layout: row(m) = quad*4 + reg, col(n) = lane15
    float* redL = (float*)&lsA[0][0][0];   // [wn][128], buffer dead post-loop
    #pragma unroll
    for (int sm = 0; sm < 4; sm++) {
        #pragma unroll
        for (int rr = 0; rr < 4; rr++) {
            float s = 0.f;
            #pragma unroll
            for (int sn = 0; sn < 4; sn++) {
                float x = acc[sm][sn][rr] + dp[sn];
                float e  = __builtin_amdgcn_exp2f(x * 2.8853900817779268f);
                float th = 1.f - 2.f * __builtin_amdgcn_rcpf(e + 1.f);
                s += th * vv[sn];
            }
            s += __shfl_xor(s, 1, 64);
            s += __shfl_xor(s, 2, 64);
            s += __shfl_xor(s, 4, 64);
            s += __shfl_xor(s, 8, 64);
            if (lane15 == 0) {
                int mlocal = wm * 64 + sm * 16 + quad * 4 + rr;
                redL[wn * 128 + mlocal] = s;
            }
        }
    }
    __syncthreads();
    if (t < 128) {
        float s = redL[t] + redL[128 + t] + redL[256 + t] + redL[384 + t];
        scores_part[((size_t)nb << 15) + m0 + t] = s;
    }
}

// ---------------------------------------------------------------------------
// K3: sum 4 partials + row softmax over S=1024 per batch row
// ---------------------------------------------------------------------------
__global__ __launch_bounds__(256) void k_softmax(const float* __restrict__ sp,
                                                 float* __restrict__ out) {
    __shared__ float red[8];
    const int b = blockIdx.x, t = threadIdx.x;
    float x[4];
    #pragma unroll
    for (int i = 0; i < 4; i++) {
        size_t idx = (size_t)b * SS + t + i * 256;
        x[i] = sp[idx] + sp[(1u << 15) + idx] + sp[(2u << 15) + idx] +
               sp[(3u << 15) + idx];
    }
    float mx = fmaxf(fmaxf(x[0], x[1]), fmaxf(x[2], x[3]));
    #pragma unroll
    for (int d = 1; d < 64; d <<= 1) mx = fmaxf(mx, __shfl_xor(mx, d, 64));
    if ((t & 63) == 0) red[t >> 6] = mx;
    __syncthreads();
    mx = fmaxf(fmaxf(red[0], red[1]), fmaxf(red[2], red[3]));
    float e[4], s = 0.f;
    #pragma unroll
    for (int i = 0; i < 4; i++) {
        e[i] = __builtin_amdgcn_exp2f((x[i] - mx) * 1.4426950408889634f);
        s += e[i];
    }
    #pragma unroll
    for (int d = 1; d < 64; d <<= 1) s += __shfl_xor(s, d, 64);
    if ((t & 63) == 0) red[4 + (t >> 6)] = s;
    __syncthreads();
    s = red[4] + red[5] + red[6] + red[7];
    float inv = 1.f / s;
    #pragma unroll
    for (int i = 0; i < 4; i++) out[(size_t)b * SS + t + i * 256] = e[i] * inv;
}

// ---------------------------------------------------------------------------
extern "C" void kernel_launch(void* const* d_in, const int* in_sizes, int n_in,
                              void* d_out, int out_size, void* d_ws, size_t ws_size,
                              hipStream_t stream) {
    const float* dh   = (const float*)d_in[0];  // (32,1024)
    const float* enc  = (const float*)d_in[1];  // (32,1024,1024)
    const float* W    = (const float*)d_in[2];  // (2048,1024)
    const float* bias = (const float*)d_in[3];  // (1024,)
    const float* v    = (const float*)d_in[4];  // (1024,)
    float* out = (float*)d_out;

    char* ws = (char*)d_ws;
    half_t* Wt2   = (half_t*)ws;                                     // 2 MB
    float*  decp  = (float*)(ws + 2u * 1024 * 1024);                 // 128 KB
    float*  spart = (float*)(ws + 2u * 1024 * 1024 + 128 * 1024);    // 512 KB
    float*  dpart = (float*)(ws + 2u * 1024 * 1024 + 640 * 1024);    // 1 MB

    k_wt     <<<128, 256, 0, stream>>>(W, Wt2);
    k_dp1    <<<128, 256, 0, stream>>>(dh, W, dpart);
    k_dp2    <<<128, 256, 0, stream>>>(dpart, bias, decp);
    k_main   <<<1024, 512, 0, stream>>>(enc, Wt2, decp, v, spart);
    k_softmax<<<32, 256, 0, stream>>>(spart, out);
}